// Round 2
// baseline (503.070 us; speedup 1.0000x reference)
//
#include <hip/hip_runtime.h>
#include <hip/hip_bf16.h>
#include <stdint.h>

#define NB 50000     // batch rows
#define KN 32        // neighbors
#define NN 200000    // nodes
#define DD 256       // feature dim
#define EE 256       // embed dim
// fused GEMM: M=NB, K=512, N=EE

typedef unsigned short u16;
typedef __attribute__((ext_vector_type(8))) short bf16x8;
typedef __attribute__((ext_vector_type(4))) float f32x4;

static __device__ __forceinline__ u16 f2bf(float f) {
  __hip_bfloat16 h = __float2bfloat16(f);
  return *reinterpret_cast<u16*>(&h);
}
static __device__ __forceinline__ float bf2f(u16 u) {
  return __uint_as_float(((unsigned)u) << 16);
}

#if defined(__has_builtin)
#if __has_builtin(__builtin_amdgcn_global_load_lds)
#define HAVE_GLL 1
#endif
#endif

// async global->LDS, 16B per lane. LDS dest must be linear (base + lane*16).
static __device__ __forceinline__ void stage16(const u16* g, u16* l) {
#ifdef HAVE_GLL
  __builtin_amdgcn_global_load_lds((const __attribute__((address_space(1))) void*)g,
                                   (__attribute__((address_space(3))) void*)l, 16, 0, 0);
#else
  *(uint4*)l = *(const uint4*)g;
#endif
}

// ---------------- kernel 1: Wc = W_init @ Wf_top (f32), bc = b_init @ Wf_top + b_final
__global__ void wc_kernel(const float* __restrict__ Wi, const float* __restrict__ bi,
                          const float* __restrict__ Wf, const float* __restrict__ bf,
                          float* __restrict__ Wc, float* __restrict__ bc) {
  const int e = threadIdx.x;
  const int d = blockIdx.x;
  if (d < DD) {
    const float* wrow = Wi + (size_t)d * DD;
    float acc = 0.f;
    for (int t = 0; t < DD; ++t)
      acc = fmaf(wrow[t], Wf[(size_t)t * EE + e], acc);
    Wc[(size_t)d * EE + e] = acc;
  } else {
    float acc = bf[e];
    for (int t = 0; t < DD; ++t)
      acc = fmaf(bi[t], Wf[(size_t)t * EE + e], acc);
    bc[e] = acc;
  }
}

// ---------------- kernel 2: Bt[e][0..511] bf16 = [Wc[:,e] | Wf_bot[:,e]]
__global__ void wt_kernel(const float* __restrict__ Wc, const float* __restrict__ Wf,
                          u16* __restrict__ Bt) {
  const int e = blockIdx.x, d = threadIdx.x;
  Bt[(size_t)e * 512 + d]       = f2bf(Wc[(size_t)d * EE + e]);
  Bt[(size_t)e * 512 + 256 + d] = f2bf(Wf[(size_t)(DD + d) * EE + e]);
}

// ---------------- kernel 3: features f32 -> bf16
__global__ void cvt_kernel(const float* __restrict__ in, u16* __restrict__ out, int n4) {
  int i = blockIdx.x * blockDim.x + threadIdx.x;
  const int stride = gridDim.x * blockDim.x;
  for (; i < n4; i += stride) {
    float4 v = ((const float4*)in)[i];
    ushort4 o;
    o.x = f2bf(v.x); o.y = f2bf(v.y); o.z = f2bf(v.z); o.w = f2bf(v.w);
    ((ushort4*)out)[i] = o;
  }
}

// ---------------- kernel 4: aggregation (unchanged; 122us @3.8TB/s measured)
__global__ void agg_kernel(const int* __restrict__ nodes,
                           const int* __restrict__ nidx,
                           const float* __restrict__ nw,
                           const u16* __restrict__ f,
                           u16* __restrict__ combined) {
  const int wave = threadIdx.x >> 6;
  const int lane = threadIdx.x & 63;
  const int b = blockIdx.x * 4 + wave;

  int idx = 0; float w = 0.f;
  if (lane < KN) {
    idx = nidx[(size_t)b * KN + lane];
    w   = nw[(size_t)b * KN + lane];
  }
  float s = w;
  #pragma unroll
  for (int off = 32; off >= 1; off >>= 1) s += __shfl_xor(s, off);
  const float inv = 1.f / s;

  float a0 = 0.f, a1 = 0.f, a2 = 0.f, a3 = 0.f;
  #pragma unroll
  for (int k = 0; k < KN; ++k) {
    const int   ik = __builtin_amdgcn_readlane(idx, k);
    const float wk = __uint_as_float(__builtin_amdgcn_readlane(__float_as_uint(w), k)) * inv;
    ushort4 v = *(const ushort4*)(f + (size_t)ik * DD + lane * 4);
    a0 = fmaf(wk, bf2f(v.x), a0);
    a1 = fmaf(wk, bf2f(v.y), a1);
    a2 = fmaf(wk, bf2f(v.z), a2);
    a3 = fmaf(wk, bf2f(v.w), a3);
  }
  const int node = nodes[b];
  ushort4 sv = *(const ushort4*)(f + (size_t)node * DD + lane * 4);
  ushort4 nv; nv.x = f2bf(a0); nv.y = f2bf(a1); nv.z = f2bf(a2); nv.w = f2bf(a3);
  *(ushort4*)(combined + (size_t)b * 512 + lane * 4) = sv;
  *(ushort4*)(combined + (size_t)b * 512 + 256 + lane * 4) = nv;
}

// ---------------- kernel 5: GEMM  out = swish(combined @ Bt^T + bc)
// A [M][512] bf16 row-major, Bt [256][512] bf16 (row e = output col e, K-contig)
// 128x128 tile, BK=32, double-buffered global_load_lds, XOR-swizzled LDS.
#define BM 128
#define BN 128
#define BK 32
#define NSTEP 16          // 512 / BK
#define LROW 32           // u16 per LDS row (64 B)

__global__ __launch_bounds__(256) void gemm_kernel(const u16* __restrict__ A,
                                                   const u16* __restrict__ Bt,
                                                   const float* __restrict__ bc,
                                                   float* __restrict__ out, int M) {
  __shared__ u16 sA[2][BM * LROW];
  __shared__ u16 sB[2][BN * LROW];
  const int tid = threadIdx.x;
  const int l = tid & 63, wv = tid >> 6;
  const int wm = wv >> 1, wn = wv & 1;

  // bijective XCD swizzle (m204): consecutive swizzled ids stay on one XCD,
  // and (mb) pairs (nb=0,1) are consecutive -> A-panel L2 reuse on that XCD.
  int id = blockIdx.x;
  {
    const int nwg = gridDim.x;
    const int q = nwg >> 3, r = nwg & 7;
    const int x = id & 7, p = id >> 3;
    id = (x < r ? x * (q + 1) : r * (q + 1) + (x - r) * q) + p;
  }
  const int m0 = (id >> 1) * BM;
  const int n0 = (id & 1) * BN;

  // ---- staging addressing: wave-load w covers 16 rows of 64B.
  // lane l: row = 16w + (l>>2), phys slot p = l&3, global slot = p ^ ((row>>1)&3)
  //        = (l&3) ^ ((l>>3)&3). LDS dest linear: w*512 + l*8 (u16).
  const int srow  = l >> 2;
  const int gslot = (l & 3) ^ ((l >> 3) & 3);
  const int w0 = wv * 2;                       // this wave's 2 chunk indices
  int ar0 = m0 + w0 * 16 + srow;       if (ar0 >= M) ar0 = M - 1;
  int ar1 = m0 + (w0 + 1) * 16 + srow; if (ar1 >= M) ar1 = M - 1;
  const u16* gA0 = A + (size_t)ar0 * 512 + gslot * 8;
  const u16* gA1 = A + (size_t)ar1 * 512 + gslot * 8;
  const u16* gB0 = Bt + (size_t)(n0 + w0 * 16 + srow) * 512 + gslot * 8;
  const u16* gB1 = Bt + (size_t)(n0 + (w0 + 1) * 16 + srow) * 512 + gslot * 8;
  const int dst0 = w0 * 512 + l * 8;
  const int dst1 = dst0 + 512;

  // ---- fragment read addressing (swizzled): row stride 32 u16,
  // slot' = (l>>4) ^ ((row>>1)&3), (row>>1)&3 == (l>>1)&3 for row = 16a + (l&15)
  const int fr = l & 15;
  const int slotr = (l >> 4) ^ ((l >> 1) & 3);
  int offA[4], offB[4];
  #pragma unroll
  for (int mf = 0; mf < 4; ++mf) offA[mf] = (wm * 64 + mf * 16 + fr) * LROW + slotr * 8;
  #pragma unroll
  for (int nf = 0; nf < 4; ++nf) offB[nf] = (wn * 64 + nf * 16 + fr) * LROW + slotr * 8;

  f32x4 acc[4][4];
  #pragma unroll
  for (int i = 0; i < 4; ++i)
    #pragma unroll
    for (int j = 0; j < 4; ++j) acc[i][j] = (f32x4){0.f, 0.f, 0.f, 0.f};

  // prologue: stage tile 0 into buf 0
  stage16(gA0, sA[0] + dst0);
  stage16(gA1, sA[0] + dst1);
  stage16(gB0, sB[0] + dst0);
  stage16(gB1, sB[0] + dst1);
  __syncthreads();

  int cur = 0;
  for (int t = 0; t < NSTEP; ++t) {
    if (t + 1 < NSTEP) {            // issue next-tile stage before compute
      const int kn = (t + 1) * BK;
      stage16(gA0 + kn, sA[cur ^ 1] + dst0);
      stage16(gA1 + kn, sA[cur ^ 1] + dst1);
      stage16(gB0 + kn, sB[cur ^ 1] + dst0);
      stage16(gB1 + kn, sB[cur ^ 1] + dst1);
    }
    bf16x8 af[4], bq[4];
    #pragma unroll
    for (int mf = 0; mf < 4; ++mf) af[mf] = *(const bf16x8*)(sA[cur] + offA[mf]);
    #pragma unroll
    for (int nf = 0; nf < 4; ++nf) bq[nf] = *(const bf16x8*)(sB[cur] + offB[nf]);
    #pragma unroll
    for (int mf = 0; mf < 4; ++mf)
      #pragma unroll
      for (int nf = 0; nf < 4; ++nf)
        acc[mf][nf] = __builtin_amdgcn_mfma_f32_16x16x32_bf16(af[mf], bq[nf], acc[mf][nf], 0, 0, 0);
    __syncthreads();                // drains vmcnt: next buffer ready
    cur ^= 1;
  }

  // epilogue: C/D layout col = lane&15, row = (lane>>4)*4 + i
  const int fcol = l & 15;
  const int frq = (l >> 4) * 4;
  #pragma unroll
  for (int nf = 0; nf < 4; ++nf) {
    const int col = n0 + wn * 64 + nf * 16 + fcol;
    const float bias = bc[col];
    #pragma unroll
    for (int mf = 0; mf < 4; ++mf) {
      const int rowb = m0 + wm * 64 + mf * 16 + frq;
      #pragma unroll
      for (int i = 0; i < 4; ++i) {
        const int row = rowb + i;
        if (row < M) {
          const float z = acc[mf][nf][i] + bias;
          out[(size_t)row * EE + col] = z * (1.f / (1.f + __expf(-z)));
        }
      }
    }
  }
}

extern "C" void kernel_launch(void* const* d_in, const int* in_sizes, int n_in,
                              void* d_out, int out_size, void* d_ws, size_t ws_size,
                              hipStream_t stream) {
  const int*   nodes = (const int*)d_in[0];
  const int*   nidx  = (const int*)d_in[1];
  const float* nw    = (const float*)d_in[2];
  const float* feat  = (const float*)d_in[3];
  const float* Wi    = (const float*)d_in[4];
  const float* bi    = (const float*)d_in[5];
  const float* Wf    = (const float*)d_in[6];
  const float* bf    = (const float*)d_in[7];
  float* out = (float*)d_out;

  char* ws = (char*)d_ws;
  const size_t OFF_COMB = 0;                         // NB*512*2 = 51,200,000
  const size_t OFF_WC   = 51200000;                  // 256*256*4
  const size_t OFF_BC   = 51462144;                  // 1,024
  const size_t OFF_BT   = 51463168;                  // 256*512*2
  const size_t OFF_FB   = 51725312;                  // NN*DD*2 = 102,400,000

  u16*   combined = (u16*)(ws + OFF_COMB);
  float* Wc       = (float*)(ws + OFF_WC);
  float* bc       = (float*)(ws + OFF_BC);
  u16*   Bt       = (u16*)(ws + OFF_BT);
  u16*   fb       = (u16*)(ws + OFF_FB);

  wc_kernel<<<DD + 1, 256, 0, stream>>>(Wi, bi, Wf, bf, Wc, bc);
  wt_kernel<<<EE, 256, 0, stream>>>(Wc, Wf, Bt);
  cvt_kernel<<<2048, 256, 0, stream>>>(feat, fb, NN * DD / 4);
  agg_kernel<<<NB / 4, 256, 0, stream>>>(nodes, nidx, nw, fb, combined);

  const int mblocks = (NB + BM - 1) / BM;            // 391
  gemm_kernel<<<mblocks * 2, 256, 0, stream>>>(combined, Bt, bc, out, NB);
}